// Round 13
// baseline (162.932 us; speedup 1.0000x reference)
//
#include <hip/hip_runtime.h>
#include <hip/hip_bf16.h>
#include <stdint.h>

// ---------- types ----------
typedef __attribute__((ext_vector_type(8))) short bf16x8;   // 8 bf16 in 4 VGPRs
typedef __attribute__((ext_vector_type(4))) float f32x4;

#define MFMA16(a, b, c) __builtin_amdgcn_mfma_f32_16x16x32_bf16(a, b, c, 0, 0, 0)

// async global->LDS, 16 bytes per lane; LDS dest = wave-uniform base + lane*16
typedef const __attribute__((address_space(1))) unsigned int* as1_u32p;
typedef __attribute__((address_space(3))) unsigned int* as3_u32p;
__device__ __forceinline__ void gl_lds16(const void* g, void* l) {
    __builtin_amdgcn_global_load_lds((as1_u32p)g, (as3_u32p)l, 16, 0, 0);
}

__device__ __forceinline__ unsigned short f2bs(float f) {
    __hip_bfloat16 h = __float2bfloat16(f);   // RNE
    unsigned short s;
    __builtin_memcpy(&s, &h, 2);
    return s;
}

// packed RNE f32x2 -> bf16x2 (v_cvt_pk_bf16_f32 on gfx950)
__device__ __forceinline__ unsigned int pk_bf16(float a, float b) {
    float2 f; f.x = a; f.y = b;
    __hip_bfloat162 h = __float22bfloat162_rn(f);
    unsigned int u;
    __builtin_memcpy(&u, &h, 4);
    return u;
}

// HAZARD LESSON (rounds 1+6): an inline-asm v_exp_f32 reading an MFMA
// accumulator directly corrupts data — INLINEASM is invisible to the
// MFMA-write -> VALU-read hazard recognizer, so the mandatory wait-states
// are not inserted. Fix: use compiler-visible exp2f() (OCML lowers it to
// v_exp_f32) so the compiler inserts the wait-states itself. This round
// tests that theory by prescaling Q (removing the shielding multiply).

// combined softmax scale: DH^-0.5 * log2(e); folded into the Q fragments in attn
#define QSCALE 0.18033688f

// ---------- fused convert: W fp32 -> bf16 (straight + transpose), ZT fp32 -> bf16 ----------
// blocks [0,256): W 64x64 tiles (LDS transpose for wtbf); blocks [256,2304): ZT stream-convert.
__global__ __launch_bounds__(256) void cvt_k(const float* __restrict__ w,
                                             const float* __restrict__ zt,
                                             unsigned short* __restrict__ wbf,
                                             unsigned short* __restrict__ wtbf,
                                             unsigned short* __restrict__ ztbf) {
    __shared__ __attribute__((aligned(16))) unsigned short T[64 * 72];  // 9 KB
    const int tid = threadIdx.x;
    if (blockIdx.x >= 256) {
        const int i = ((int)blockIdx.x - 256) * 2048 + tid * 8;
        const float4 v0 = *(const float4*)(zt + i);
        const float4 v1 = *(const float4*)(zt + i + 4);
        uint4 wv;
        wv.x = pk_bf16(v0.x, v0.y);
        wv.y = pk_bf16(v0.z, v0.w);
        wv.z = pk_bf16(v1.x, v1.y);
        wv.w = pk_bf16(v1.z, v1.w);
        *(uint4*)(ztbf + i) = wv;
        return;
    }
    const int b2 = blockIdx.x;               // 256 tiles: 16x16 of 64x64
    const int e0 = (b2 >> 4) * 64, d0 = (b2 & 15) * 64;
    const int el = tid >> 2;                 // 0..63
    const int dl = (tid & 3) * 16;           // 0,16,32,48
    const float* src = w + (size_t)(e0 + el) * 1024 + d0 + dl;
    unsigned short myv[16];
#pragma unroll
    for (int q = 0; q < 4; ++q) {
        const float4 v = *(const float4*)(src + q * 4);
        myv[q * 4 + 0] = f2bs(v.x);
        myv[q * 4 + 1] = f2bs(v.y);
        myv[q * 4 + 2] = f2bs(v.z);
        myv[q * 4 + 3] = f2bs(v.w);
    }
    // wbf straight (two 16B stores)
    *(bf16x8*)(wbf + (size_t)(e0 + el) * 1024 + d0 + dl) = *(const bf16x8*)&myv[0];
    *(bf16x8*)(wbf + (size_t)(e0 + el) * 1024 + d0 + dl + 8) = *(const bf16x8*)&myv[8];
    // LDS transpose: T[d_local][e_local] (natural)
#pragma unroll
    for (int q = 0; q < 16; ++q) T[(dl + q) * 72 + el] = myv[q];
    __syncthreads();
    // coalesced wtbf stores: row d, 64 e contiguous
#pragma unroll
    for (int p = 0; p < 2; ++p) {
        const int idx = p * 256 + tid;
        const int dd = idx >> 3, c = (idx & 7) * 8;
        const bf16x8 v = *(const bf16x8*)&T[dd * 72 + c];
        *(bf16x8*)(wtbf + (size_t)(d0 + dd) * 1024 + e0 + c) = v;
    }
}

// ---------- GEMM: C[M,N] = A[M,K] * B[N,K]^T, tile 64x128, BK=64, 4 waves ----------
// Double-buffered (48 KB LDS): stage kt+1 while computing kt; one barrier per K-step.
// LDS tiles stored as [row][64] with XOR chunk swizzle -> conflict-free ds_read_b128.
// EPI 0: C -> ztu bf16 + ztut via LDS transpose (token perm in 32-grps for attn).
// EPI 1: C -> out0, out1 fp32 via fp32 LDS transpose, float4 coalesced.
// (r12's fused fp32-A staging was neutral-negative — reverted to r11 config.)
template <int EPI>
__global__ __launch_bounds__(256, 2) void gemm_bt_k(
    const __hip_bfloat16* __restrict__ Abf, const __hip_bfloat16* __restrict__ B,
    unsigned short* __restrict__ ztu, unsigned short* __restrict__ ztut,
    float* __restrict__ out0, float* __restrict__ out1) {
    __shared__ __attribute__((aligned(16))) unsigned short smem[24576];  // 48 KB: 2 x (A 8KB + B 16KB)
    unsigned short* Tb = smem;          // EPI-0 epilogue reuse: [128][72] = 18 KB

    const int p = blockIdx.x;
    const int bm = (p & 7) * 8 + ((p >> 3) & 7);   // same-bm blocks share an XCD
    const int bn = p >> 6;
    const int tid = threadIdx.x;
    const int wave = tid >> 6, lane = tid & 63;
    const int wm = wave >> 1, wn = wave & 1;   // wave tile: 32 rows x 64 cols
    const int quad = lane >> 4, l16 = lane & 15;

    f32x4 acc[2][4] = {};

    // staging: 8-row 512-short chunks, lane covers (lrow, swizzled col group)
    const int lrow = lane >> 3;
    const int sw = (lane & 7) ^ lrow;
    const __hip_bfloat16* Ag0 = Abf + (size_t)(bm * 64 + (2 * wave) * 8 + lrow) * 1024 + sw * 8;
    const __hip_bfloat16* Ag1 = Ag0 + 8 * 1024;
    const __hip_bfloat16* Bg0 = B + (size_t)(bn * 128 + (4 * wave) * 8 + lrow) * 1024 + sw * 8;
    const __hip_bfloat16* Bg1 = Bg0 + 8 * 1024;
    const __hip_bfloat16* Bg2 = Bg0 + 16 * 1024;
    const __hip_bfloat16* Bg3 = Bg0 + 24 * 1024;

    auto stage = [&](int ko, unsigned short* sb) {
        gl_lds16(Ag0 + ko, sb + (2 * wave) * 512);
        gl_lds16(Ag1 + ko, sb + (2 * wave + 1) * 512);
        gl_lds16(Bg0 + ko, sb + 4096 + (4 * wave) * 512);
        gl_lds16(Bg1 + ko, sb + 4096 + (4 * wave + 1) * 512);
        gl_lds16(Bg2 + ko, sb + 4096 + (4 * wave + 2) * 512);
        gl_lds16(Bg3 + ko, sb + 4096 + (4 * wave + 3) * 512);
    };

    // swizzled read offsets: chunk (h*4+quad)^(l16&7); ^4 on chunk == ^32 on elems
    const int ch0 = (quad ^ (l16 & 7)) * 8;
    const int ch1 = ch0 ^ 32;
    const int raA = (wm * 32 + l16) * 64;
    const int raB = (wn * 64 + l16) * 64;

    stage(0, smem);
    __syncthreads();

    for (int kt = 0; kt < 16; ++kt) {
        unsigned short* const sb = smem + (kt & 1) * 12288;
        if (kt < 15) stage((kt + 1) << 6, smem + (((kt & 1) ^ 1) * 12288));
        bf16x8 af[2][2], bfr[2][4];
#pragma unroll
        for (int i = 0; i < 2; ++i) {
            af[0][i] = *(const bf16x8*)&sb[raA + i * 1024 + ch0];
            af[1][i] = *(const bf16x8*)&sb[raA + i * 1024 + ch1];
        }
#pragma unroll
        for (int j = 0; j < 4; ++j) {
            bfr[0][j] = *(const bf16x8*)&sb[4096 + raB + j * 1024 + ch0];
            bfr[1][j] = *(const bf16x8*)&sb[4096 + raB + j * 1024 + ch1];
        }
#pragma unroll
        for (int h = 0; h < 2; ++h)
#pragma unroll
            for (int i = 0; i < 2; ++i)
#pragma unroll
                for (int j = 0; j < 4; ++j) acc[i][j] = MFMA16(af[h][i], bfr[h][j], acc[i][j]);
        __syncthreads();
    }

    if (EPI == 0) {
        const int h = bn * 2 + wn;           // e = bn*128 + wn*64 + j*16+l16 -> j-independent
        const int bb = bm >> 5;              // batch
        const int nb = (bm & 31) * 64;       // token base within batch
        const size_t hb = (size_t)(bb * 16 + h) * 131072;
#pragma unroll
        for (int i = 0; i < 2; ++i) {
#pragma unroll
            for (int r = 0; r < 4; ++r) {
                const int n = nb + wm * 32 + i * 16 + quad * 4 + r;
                uint2 pk;
                pk.x = pk_bf16(acc[i][0][r], acc[i][1][r]);
                pk.y = pk_bf16(acc[i][2][r], acc[i][3][r]);
                // ztu: dh stored-permuted (4*l16 + j) -> one packed b64 store
                *(uint2*)(ztu + hb + n * 64 + l16 * 4) = pk;
                // Tb[e_local][np_local]: key perm within 32-groups for S^T trick:
                // n_local = wm*32 + i*16 + quad*4 + r -> np = wm*32 + quad*8 + i*4 + r
                const int npl = wm * 32 + quad * 8 + i * 4 + r;
                Tb[(wn * 64 + 0 + l16) * 72 + npl] = (unsigned short)(pk.x & 0xffff);
                Tb[(wn * 64 + 16 + l16) * 72 + npl] = (unsigned short)(pk.x >> 16);
                Tb[(wn * 64 + 32 + l16) * 72 + npl] = (unsigned short)(pk.y & 0xffff);
                Tb[(wn * 64 + 48 + l16) * 72 + npl] = (unsigned short)(pk.y >> 16);
            }
        }
        __syncthreads();
        // ztut: coalesced b128 stores, rows = natural dh, cols = permuted tokens
#pragma unroll
        for (int ee = 0; ee < 4; ++ee) {
            const int e_local = wave * 32 + ee * 8 + (lane >> 3);
            const int nc = (lane & 7) * 8;
            const bf16x8 v = *(const bf16x8*)&Tb[e_local * 72 + nc];
            const int hh = bn * 2 + (e_local >> 6);
            const int dh = e_local & 63;
            *(bf16x8*)(ztut + (size_t)(bb * 16 + hh) * 131072 + dh * 2048 + nb + nc) = v;
        }
    } else {
        // coalesced fp32 epilogue: LDS transpose [64][132] fp32, then 512B-contiguous
        // float4 stores.
        float* Tf = (float*)smem;
        // K-loop's final __syncthreads() already fenced all LDS reads.
#pragma unroll
        for (int i = 0; i < 2; ++i)
#pragma unroll
            for (int r = 0; r < 4; ++r) {
                const int ml = wm * 32 + i * 16 + quad * 4 + r;
#pragma unroll
                for (int j = 0; j < 4; ++j)
                    Tf[ml * 132 + wn * 64 + j * 16 + l16] = acc[i][j][r];
            }
        __syncthreads();
#pragma unroll
        for (int q = 0; q < 8; ++q) {
            const int idx = q * 256 + tid;        // 0..2047
            const int row = idx >> 5;             // 0..63
            const int c4 = (idx & 31) * 4;        // 0..124
            const float4 v = *(const float4*)&Tf[row * 132 + c4];
            const size_t off = (size_t)(bm * 64 + row) * 1024 + bn * 128 + c4;
            *(float4*)(out0 + off) = v;
            *(float4*)(out1 + off) = v;
        }
    }
}

// ---------- flash attention, transposed (register-P) structure ----------
// Round-11 structure (pair-unrolled 64-key tiles, 32 KB LDS, 4 blocks/CU,
// ones-MFMA denominator) with TWO linked changes that test the hazard theory:
// 1) QSCALE folded into the Q fragments once at load (removes 16 v_mul per
//    tile per wave from the busiest pipe, VALUBusy 47%).
// 2) exp2 via compiler-visible exp2f() instead of inline-asm v_exp_f32 —
//    the compiler's hazard recognizer now sees the MFMA->exp dependency and
//    inserts the mandatory wait-states that the asm path lacked (the r1/r6
//    failure mechanism once the shielding multiply was removed).
__global__ __launch_bounds__(256, 2) void attn_k(const unsigned short* __restrict__ ztu,
                                                 const unsigned short* __restrict__ ztut,
                                                 unsigned short* __restrict__ ssa) {
    __shared__ __attribute__((aligned(16))) unsigned short Kt[2][4096];   // [key][d-sw]
    __shared__ __attribute__((aligned(16))) unsigned short Vt[2][4096];   // [d][key'-sw]
    const int p = blockIdx.x;
    const int ii = p >> 3;
    const int bh = (p & 7) * 4 + (ii >> 5);   // 32 bh, XCD-swizzled
    const int qt = ii & 31;                   // 32 q-tiles of 64 rows
    const int tid = threadIdx.x, wave = tid >> 6, lane = tid & 63;
    const int quad = lane >> 4, l16 = lane & 15;
    const unsigned short* base = ztu + (size_t)bh * 131072;
    const unsigned short* baseT = ztut + (size_t)bh * 131072;

    // Q fragments (B-operand): this wave's 16 q-rows, 2 k-chunks, QSCALE folded in
    const int qrow = qt * 64 + wave * 16;
    bf16x8 qa[2];
    qa[0] = *(const bf16x8*)(base + (qrow + l16) * 64 + quad * 8);
    qa[1] = *(const bf16x8*)(base + (qrow + l16) * 64 + 32 + quad * 8);
#pragma unroll
    for (int w = 0; w < 2; ++w) {
        bf16x8 v = qa[w], r;
#pragma unroll
        for (int z = 0; z < 8; z += 2) {
            const float f0 = __uint_as_float(((unsigned)(unsigned short)v[z]) << 16) * QSCALE;
            const float f1 = __uint_as_float(((unsigned)(unsigned short)v[z + 1]) << 16) * QSCALE;
            const unsigned u = pk_bf16(f0, f1);
            r[z] = (short)(u & 0xffff);
            r[z + 1] = (short)(u >> 16);
        }
        qa[w] = r;
    }

    f32x4 o[4] = {};
    f32x4 lacc = {};   // softmax denominator via ones-MFMA (all rows = col sum)
    bf16x8 ones;
#pragma unroll
    for (int z = 0; z < 8; ++z) ones[z] = (short)0x3f80;   // bf16 1.0

    // staging: tile = 8 chunks of 1KB; wave w stages chunks {2w,2w+1} of K and V.
    // chunk c covers rows c*8+(lane>>3); swizzled source group = (lane&7)^(lane>>3)
    const int c0 = wave * 2, c1 = c0 + 1;
    const int lrow = lane >> 3;
    const int sw = (lane & 7) ^ lrow;
    const unsigned short* gK0 = base + (c0 * 8 + lrow) * 64 + sw * 8;
    const unsigned short* gK1 = base + (c1 * 8 + lrow) * 64 + sw * 8;
    const unsigned short* gV0 = baseT + (size_t)(c0 * 8 + lrow) * 2048 + sw * 8;
    const unsigned short* gV1 = baseT + (size_t)(c1 * 8 + lrow) * 2048 + sw * 8;

    // swizzled read offsets (elements)
    const int swq = (quad ^ (l16 & 7));
    const int koff0 = l16 * 64 + swq * 8;          // + {nf,df}*1024 per row-group
    const int koff1 = l16 * 64 + (swq ^ 4) * 8;

    for (int tp = 0; tp < 16; ++tp) {
        const int t0 = tp * 2;                     // tiles t0 and t0+1 this pass
        gl_lds16(gK0 + t0 * 4096, &Kt[0][c0 * 512]);
        gl_lds16(gK1 + t0 * 4096, &Kt[0][c1 * 512]);
        gl_lds16(gV0 + t0 * 64, &Vt[0][c0 * 512]);
        gl_lds16(gV1 + t0 * 64, &Vt[0][c1 * 512]);
        gl_lds16(gK0 + t0 * 4096 + 4096, &Kt[1][c0 * 512]);
        gl_lds16(gK1 + t0 * 4096 + 4096, &Kt[1][c1 * 512]);
        gl_lds16(gV0 + t0 * 64 + 64, &Vt[1][c0 * 512]);
        gl_lds16(gV1 + t0 * 64 + 64, &Vt[1][c1 * 512]);
        __syncthreads();

#pragma unroll
        for (int u = 0; u < 2; ++u) {
            // S^T = K * Q^T: C[m=key nf*16+quad*4+r][n=q=l16]  (QSCALE in Q)
            f32x4 st[4];
#pragma unroll
            for (int nf = 0; nf < 4; ++nf) {
                const bf16x8 kb0 = *(const bf16x8*)&Kt[u][nf * 1024 + koff0];
                const bf16x8 kb1 = *(const bf16x8*)&Kt[u][nf * 1024 + koff1];
                f32x4 z = {0.f, 0.f, 0.f, 0.f};
                z = MFMA16(kb0, qa[0], z);
                z = MFMA16(kb1, qa[1], z);
                st[nf] = z;
            }

            // exp in registers via compiler-visible exp2f (hazard-safe; see note)
            float e[16];
#pragma unroll
            for (int nf = 0; nf < 4; ++nf)
#pragma unroll
                for (int r = 0; r < 4; ++r) e[nf * 4 + r] = exp2f(st[nf][r]);
            bf16x8 pa[2];
            uint4 u0, u1;
            u0.x = pk_bf16(e[0], e[1]);   u0.y = pk_bf16(e[2], e[3]);
            u0.z = pk_bf16(e[4], e[5]);   u0.w = pk_bf16(e[6], e[7]);
            u1.x = pk_bf16(e[8], e[9]);   u1.y = pk_bf16(e[10], e[11]);
            u1.z = pk_bf16(e[12], e[13]); u1.w = pk_bf16(e[14], e[15]);
            __builtin_memcpy(&pa[0], &u0, 16);
            __builtin_memcpy(&pa[1], &u1, 16);
            // denominator: D[m][q] = sum_k P^T[k][q] (same bf16 P as numerator)
            lacc = MFMA16(ones, pa[0], lacc);
            lacc = MFMA16(ones, pa[1], lacc);

            // O^T += V^T * P^T: A = Vt[d][key'-sw], B = pa (registers)
#pragma unroll
            for (int df = 0; df < 4; ++df) {
                const bf16x8 vb0 = *(const bf16x8*)&Vt[u][df * 1024 + koff0];
                const bf16x8 vb1 = *(const bf16x8*)&Vt[u][df * 1024 + koff1];
                o[df] = MFMA16(vb0, pa[0], o[df]);
                o[df] = MFMA16(vb1, pa[1], o[df]);
            }
        }
        __syncthreads();
    }

    // epilogue: lacc already holds the full row sum for q-col l16
    const int b = bh >> 4, h = bh & 15;
    const float inv = 1.0f / lacc[0];
    const int token = b * 2048 + qrow + l16;
#pragma unroll
    for (int df = 0; df < 4; ++df) {
        uint2 pk;
        pk.x = pk_bf16(o[df][0] * inv, o[df][1] * inv);
        pk.y = pk_bf16(o[df][2] * inv, o[df][3] * inv);
        *(uint2*)(ssa + (size_t)token * 1024 + h * 64 + df * 16 + quad * 4) = pk;
    }
}

// ---------- launch ----------
extern "C" void kernel_launch(void* const* d_in, const int* in_sizes, int n_in,
                              void* d_out, int out_size, void* d_ws, size_t ws_size,
                              hipStream_t stream) {
    const float* ZT = (const float*)d_in[0];  // (2,2048,1024)
    const float* W = (const float*)d_in[1];   // (1024,1024)
    float* out = (float*)d_out;               // 2 x 4194304 fp32
    char* ws = (char*)d_ws;

    unsigned short* wbf   = (unsigned short*)(ws);                       // 2 MB
    unsigned short* wtbf  = (unsigned short*)(ws + 2u * 1024 * 1024);    // 2 MB
    unsigned short* ztu   = (unsigned short*)(ws + 4u * 1024 * 1024);    // 8 MB (b,h,n,dh_perm)
    unsigned short* ztut  = (unsigned short*)(ws + 12u * 1024 * 1024);   // 8 MB (b,h,dh,n_perm32)
    unsigned short* scr20 = (unsigned short*)(ws + 20u * 1024 * 1024);   // 8 MB: ztbf, then ssabf

    // W (straight + transpose) and ZT fp32->bf16, one launch (r11 config)
    cvt_k<<<2304, 256, 0, stream>>>(W, ZT, wbf, wtbf, scr20);
    // ZTU = ZT @ W^T (bf16 A via gl_lds16, double-buffered)
    gemm_bt_k<0><<<512, 256, 0, stream>>>((const __hip_bfloat16*)scr20,
                                          (const __hip_bfloat16*)wbf, ztu, ztut,
                                          nullptr, nullptr);
    // flash attention (pair-unrolled tiles + Q-prescale + exp2f)
    attn_k<<<1024, 256, 0, stream>>>(ztu, ztut, scr20);
    // mssa = ssa @ W, duplicated output (coalesced float4 epilogue)
    gemm_bt_k<1><<<512, 256, 0, stream>>>((const __hip_bfloat16*)scr20,
                                          (const __hip_bfloat16*)wtbf, nullptr, nullptr,
                                          out, out + 4194304);
}

// Round 14
// 146.970 us; speedup vs baseline: 1.1086x; 1.1086x over previous
//
#include <hip/hip_runtime.h>
#include <hip/hip_bf16.h>
#include <stdint.h>

// ---------- types ----------
typedef __attribute__((ext_vector_type(8))) short bf16x8;   // 8 bf16 in 4 VGPRs
typedef __attribute__((ext_vector_type(4))) float f32x4;

#define MFMA16(a, b, c) __builtin_amdgcn_mfma_f32_16x16x32_bf16(a, b, c, 0, 0, 0)

// async global->LDS, 16 bytes per lane; LDS dest = wave-uniform base + lane*16
typedef const __attribute__((address_space(1))) unsigned int* as1_u32p;
typedef __attribute__((address_space(3))) unsigned int* as3_u32p;
__device__ __forceinline__ void gl_lds16(const void* g, void* l) {
    __builtin_amdgcn_global_load_lds((as1_u32p)g, (as3_u32p)l, 16, 0, 0);
}

__device__ __forceinline__ unsigned short f2bs(float f) {
    __hip_bfloat16 h = __float2bfloat16(f);   // RNE
    unsigned short s;
    __builtin_memcpy(&s, &h, 2);
    return s;
}

// packed RNE f32x2 -> bf16x2 (v_cvt_pk_bf16_f32 on gfx950)
__device__ __forceinline__ unsigned int pk_bf16(float a, float b) {
    float2 f; f.x = a; f.y = b;
    __hip_bfloat162 h = __float22bfloat162_rn(f);
    unsigned int u;
    __builtin_memcpy(&u, &h, 4);
    return u;
}

// exp2 via the LLVM intrinsic: exactly one v_exp_f32, AND compiler-visible —
// the MFMA-write -> VALU-read hazard recognizer schedules it correctly.
// HISTORY: inline-asm v_exp_f32 reading an MFMA accumulator directly corrupted
// data (r1/r6 — INLINEASM is invisible to the hazard recognizer; the QSCALE
// multiply was accidentally acting as the shield). r13 proved prescale+
// compiler-visible exp is CORRECT but OCML exp2f's guard code cost +17 us.
__device__ __forceinline__ float exp2_fast(float x) {
    return __builtin_amdgcn_exp2f(x);
}

// combined softmax scale: DH^-0.5 * log2(e); folded into the Q fragments in attn
#define QSCALE 0.18033688f

// ---------- fused convert: W fp32 -> bf16 (straight + transpose), ZT fp32 -> bf16 ----------
// blocks [0,256): W 64x64 tiles (LDS transpose for wtbf); blocks [256,2304): ZT stream-convert.
__global__ __launch_bounds__(256) void cvt_k(const float* __restrict__ w,
                                             const float* __restrict__ zt,
                                             unsigned short* __restrict__ wbf,
                                             unsigned short* __restrict__ wtbf,
                                             unsigned short* __restrict__ ztbf) {
    __shared__ __attribute__((aligned(16))) unsigned short T[64 * 72];  // 9 KB
    const int tid = threadIdx.x;
    if (blockIdx.x >= 256) {
        const int i = ((int)blockIdx.x - 256) * 2048 + tid * 8;
        const float4 v0 = *(const float4*)(zt + i);
        const float4 v1 = *(const float4*)(zt + i + 4);
        uint4 wv;
        wv.x = pk_bf16(v0.x, v0.y);
        wv.y = pk_bf16(v0.z, v0.w);
        wv.z = pk_bf16(v1.x, v1.y);
        wv.w = pk_bf16(v1.z, v1.w);
        *(uint4*)(ztbf + i) = wv;
        return;
    }
    const int b2 = blockIdx.x;               // 256 tiles: 16x16 of 64x64
    const int e0 = (b2 >> 4) * 64, d0 = (b2 & 15) * 64;
    const int el = tid >> 2;                 // 0..63
    const int dl = (tid & 3) * 16;           // 0,16,32,48
    const float* src = w + (size_t)(e0 + el) * 1024 + d0 + dl;
    unsigned short myv[16];
#pragma unroll
    for (int q = 0; q < 4; ++q) {
        const float4 v = *(const float4*)(src + q * 4);
        myv[q * 4 + 0] = f2bs(v.x);
        myv[q * 4 + 1] = f2bs(v.y);
        myv[q * 4 + 2] = f2bs(v.z);
        myv[q * 4 + 3] = f2bs(v.w);
    }
    // wbf straight (two 16B stores)
    *(bf16x8*)(wbf + (size_t)(e0 + el) * 1024 + d0 + dl) = *(const bf16x8*)&myv[0];
    *(bf16x8*)(wbf + (size_t)(e0 + el) * 1024 + d0 + dl + 8) = *(const bf16x8*)&myv[8];
    // LDS transpose: T[d_local][e_local] (natural)
#pragma unroll
    for (int q = 0; q < 16; ++q) T[(dl + q) * 72 + el] = myv[q];
    __syncthreads();
    // coalesced wtbf stores: row d, 64 e contiguous
#pragma unroll
    for (int p = 0; p < 2; ++p) {
        const int idx = p * 256 + tid;
        const int dd = idx >> 3, c = (idx & 7) * 8;
        const bf16x8 v = *(const bf16x8*)&T[dd * 72 + c];
        *(bf16x8*)(wtbf + (size_t)(d0 + dd) * 1024 + e0 + c) = v;
    }
}

// ---------- GEMM: C[M,N] = A[M,K] * B[N,K]^T, tile 64x128, BK=64, 4 waves ----------
// Double-buffered (48 KB LDS): stage kt+1 while computing kt; one barrier per K-step.
// LDS tiles stored as [row][64] with XOR chunk swizzle -> conflict-free ds_read_b128.
// EPI 0: C -> ztu bf16 + ztut via LDS transpose (token perm in 32-grps for attn).
// EPI 1: C -> out0, out1 fp32 via fp32 LDS transpose, float4 coalesced.
template <int EPI>
__global__ __launch_bounds__(256, 2) void gemm_bt_k(
    const __hip_bfloat16* __restrict__ Abf, const __hip_bfloat16* __restrict__ B,
    unsigned short* __restrict__ ztu, unsigned short* __restrict__ ztut,
    float* __restrict__ out0, float* __restrict__ out1) {
    __shared__ __attribute__((aligned(16))) unsigned short smem[24576];  // 48 KB: 2 x (A 8KB + B 16KB)
    unsigned short* Tb = smem;          // EPI-0 epilogue reuse: [128][72] = 18 KB

    const int p = blockIdx.x;
    const int bm = (p & 7) * 8 + ((p >> 3) & 7);   // same-bm blocks share an XCD
    const int bn = p >> 6;
    const int tid = threadIdx.x;
    const int wave = tid >> 6, lane = tid & 63;
    const int wm = wave >> 1, wn = wave & 1;   // wave tile: 32 rows x 64 cols
    const int quad = lane >> 4, l16 = lane & 15;

    f32x4 acc[2][4] = {};

    // staging: 8-row 512-short chunks, lane covers (lrow, swizzled col group)
    const int lrow = lane >> 3;
    const int sw = (lane & 7) ^ lrow;
    const __hip_bfloat16* Ag0 = Abf + (size_t)(bm * 64 + (2 * wave) * 8 + lrow) * 1024 + sw * 8;
    const __hip_bfloat16* Ag1 = Ag0 + 8 * 1024;
    const __hip_bfloat16* Bg0 = B + (size_t)(bn * 128 + (4 * wave) * 8 + lrow) * 1024 + sw * 8;
    const __hip_bfloat16* Bg1 = Bg0 + 8 * 1024;
    const __hip_bfloat16* Bg2 = Bg0 + 16 * 1024;
    const __hip_bfloat16* Bg3 = Bg0 + 24 * 1024;

    auto stage = [&](int ko, unsigned short* sb) {
        gl_lds16(Ag0 + ko, sb + (2 * wave) * 512);
        gl_lds16(Ag1 + ko, sb + (2 * wave + 1) * 512);
        gl_lds16(Bg0 + ko, sb + 4096 + (4 * wave) * 512);
        gl_lds16(Bg1 + ko, sb + 4096 + (4 * wave + 1) * 512);
        gl_lds16(Bg2 + ko, sb + 4096 + (4 * wave + 2) * 512);
        gl_lds16(Bg3 + ko, sb + 4096 + (4 * wave + 3) * 512);
    };

    // swizzled read offsets: chunk (h*4+quad)^(l16&7); ^4 on chunk == ^32 on elems
    const int ch0 = (quad ^ (l16 & 7)) * 8;
    const int ch1 = ch0 ^ 32;
    const int raA = (wm * 32 + l16) * 64;
    const int raB = (wn * 64 + l16) * 64;

    stage(0, smem);
    __syncthreads();

    for (int kt = 0; kt < 16; ++kt) {
        unsigned short* const sb = smem + (kt & 1) * 12288;
        if (kt < 15) stage((kt + 1) << 6, smem + (((kt & 1) ^ 1) * 12288));
        bf16x8 af[2][2], bfr[2][4];
#pragma unroll
        for (int i = 0; i < 2; ++i) {
            af[0][i] = *(const bf16x8*)&sb[raA + i * 1024 + ch0];
            af[1][i] = *(const bf16x8*)&sb[raA + i * 1024 + ch1];
        }
#pragma unroll
        for (int j = 0; j < 4; ++j) {
            bfr[0][j] = *(const bf16x8*)&sb[4096 + raB + j * 1024 + ch0];
            bfr[1][j] = *(const bf16x8*)&sb[4096 + raB + j * 1024 + ch1];
        }
#pragma unroll
        for (int h = 0; h < 2; ++h)
#pragma unroll
            for (int i = 0; i < 2; ++i)
#pragma unroll
                for (int j = 0; j < 4; ++j) acc[i][j] = MFMA16(af[h][i], bfr[h][j], acc[i][j]);
        __syncthreads();
    }

    if (EPI == 0) {
        const int h = bn * 2 + wn;           // e = bn*128 + wn*64 + j*16+l16 -> j-independent
        const int bb = bm >> 5;              // batch
        const int nb = (bm & 31) * 64;       // token base within batch
        const size_t hb = (size_t)(bb * 16 + h) * 131072;
#pragma unroll
        for (int i = 0; i < 2; ++i) {
#pragma unroll
            for (int r = 0; r < 4; ++r) {
                const int n = nb + wm * 32 + i * 16 + quad * 4 + r;
                uint2 pk;
                pk.x = pk_bf16(acc[i][0][r], acc[i][1][r]);
                pk.y = pk_bf16(acc[i][2][r], acc[i][3][r]);
                // ztu: dh stored-permuted (4*l16 + j) -> one packed b64 store
                *(uint2*)(ztu + hb + n * 64 + l16 * 4) = pk;
                // Tb[e_local][np_local]: key perm within 32-groups for S^T trick:
                // n_local = wm*32 + i*16 + quad*4 + r -> np = wm*32 + quad*8 + i*4 + r
                const int npl = wm * 32 + quad * 8 + i * 4 + r;
                Tb[(wn * 64 + 0 + l16) * 72 + npl] = (unsigned short)(pk.x & 0xffff);
                Tb[(wn * 64 + 16 + l16) * 72 + npl] = (unsigned short)(pk.x >> 16);
                Tb[(wn * 64 + 32 + l16) * 72 + npl] = (unsigned short)(pk.y & 0xffff);
                Tb[(wn * 64 + 48 + l16) * 72 + npl] = (unsigned short)(pk.y >> 16);
            }
        }
        __syncthreads();
        // ztut: coalesced b128 stores, rows = natural dh, cols = permuted tokens
#pragma unroll
        for (int ee = 0; ee < 4; ++ee) {
            const int e_local = wave * 32 + ee * 8 + (lane >> 3);
            const int nc = (lane & 7) * 8;
            const bf16x8 v = *(const bf16x8*)&Tb[e_local * 72 + nc];
            const int hh = bn * 2 + (e_local >> 6);
            const int dh = e_local & 63;
            *(bf16x8*)(ztut + (size_t)(bb * 16 + hh) * 131072 + dh * 2048 + nb + nc) = v;
        }
    } else {
        // coalesced fp32 epilogue: LDS transpose [64][132] fp32, then 512B-contiguous
        // float4 stores.
        float* Tf = (float*)smem;
        // K-loop's final __syncthreads() already fenced all LDS reads.
#pragma unroll
        for (int i = 0; i < 2; ++i)
#pragma unroll
            for (int r = 0; r < 4; ++r) {
                const int ml = wm * 32 + i * 16 + quad * 4 + r;
#pragma unroll
                for (int j = 0; j < 4; ++j)
                    Tf[ml * 132 + wn * 64 + j * 16 + l16] = acc[i][j][r];
            }
        __syncthreads();
#pragma unroll
        for (int q = 0; q < 8; ++q) {
            const int idx = q * 256 + tid;        // 0..2047
            const int row = idx >> 5;             // 0..63
            const int c4 = (idx & 31) * 4;        // 0..124
            const float4 v = *(const float4*)&Tf[row * 132 + c4];
            const size_t off = (size_t)(bm * 64 + row) * 1024 + bn * 128 + c4;
            *(float4*)(out0 + off) = v;
            *(float4*)(out1 + off) = v;
        }
    }
}

// ---------- flash attention, transposed (register-P) structure ----------
// Round-11 structure (pair-unrolled 64-key tiles, 32 KB LDS, 4 blocks/CU,
// ones-MFMA denominator) + Q-prescale (r13-verified correct) + single-instr
// exp via __builtin_amdgcn_exp2f (compiler-visible -> hazard-safe, unlike
// the r1/r6 inline asm; single v_exp_f32, unlike r13's guarded OCML exp2f).
__global__ __launch_bounds__(256, 2) void attn_k(const unsigned short* __restrict__ ztu,
                                                 const unsigned short* __restrict__ ztut,
                                                 unsigned short* __restrict__ ssa) {
    __shared__ __attribute__((aligned(16))) unsigned short Kt[2][4096];   // [key][d-sw]
    __shared__ __attribute__((aligned(16))) unsigned short Vt[2][4096];   // [d][key'-sw]
    const int p = blockIdx.x;
    const int ii = p >> 3;
    const int bh = (p & 7) * 4 + (ii >> 5);   // 32 bh, XCD-swizzled
    const int qt = ii & 31;                   // 32 q-tiles of 64 rows
    const int tid = threadIdx.x, wave = tid >> 6, lane = tid & 63;
    const int quad = lane >> 4, l16 = lane & 15;
    const unsigned short* base = ztu + (size_t)bh * 131072;
    const unsigned short* baseT = ztut + (size_t)bh * 131072;

    // Q fragments (B-operand): this wave's 16 q-rows, 2 k-chunks, QSCALE folded in
    const int qrow = qt * 64 + wave * 16;
    bf16x8 qa[2];
    qa[0] = *(const bf16x8*)(base + (qrow + l16) * 64 + quad * 8);
    qa[1] = *(const bf16x8*)(base + (qrow + l16) * 64 + 32 + quad * 8);
#pragma unroll
    for (int w = 0; w < 2; ++w) {
        bf16x8 v = qa[w], r;
#pragma unroll
        for (int z = 0; z < 8; z += 2) {
            const float f0 = __uint_as_float(((unsigned)(unsigned short)v[z]) << 16) * QSCALE;
            const float f1 = __uint_as_float(((unsigned)(unsigned short)v[z + 1]) << 16) * QSCALE;
            const unsigned u = pk_bf16(f0, f1);
            r[z] = (short)(u & 0xffff);
            r[z + 1] = (short)(u >> 16);
        }
        qa[w] = r;
    }

    f32x4 o[4] = {};
    f32x4 lacc = {};   // softmax denominator via ones-MFMA (all rows = col sum)
    bf16x8 ones;
#pragma unroll
    for (int z = 0; z < 8; ++z) ones[z] = (short)0x3f80;   // bf16 1.0

    // staging: tile = 8 chunks of 1KB; wave w stages chunks {2w,2w+1} of K and V.
    // chunk c covers rows c*8+(lane>>3); swizzled source group = (lane&7)^(lane>>3)
    const int c0 = wave * 2, c1 = c0 + 1;
    const int lrow = lane >> 3;
    const int sw = (lane & 7) ^ lrow;
    const unsigned short* gK0 = base + (c0 * 8 + lrow) * 64 + sw * 8;
    const unsigned short* gK1 = base + (c1 * 8 + lrow) * 64 + sw * 8;
    const unsigned short* gV0 = baseT + (size_t)(c0 * 8 + lrow) * 2048 + sw * 8;
    const unsigned short* gV1 = baseT + (size_t)(c1 * 8 + lrow) * 2048 + sw * 8;

    // swizzled read offsets (elements)
    const int swq = (quad ^ (l16 & 7));
    const int koff0 = l16 * 64 + swq * 8;          // + {nf,df}*1024 per row-group
    const int koff1 = l16 * 64 + (swq ^ 4) * 8;

    for (int tp = 0; tp < 16; ++tp) {
        const int t0 = tp * 2;                     // tiles t0 and t0+1 this pass
        gl_lds16(gK0 + t0 * 4096, &Kt[0][c0 * 512]);
        gl_lds16(gK1 + t0 * 4096, &Kt[0][c1 * 512]);
        gl_lds16(gV0 + t0 * 64, &Vt[0][c0 * 512]);
        gl_lds16(gV1 + t0 * 64, &Vt[0][c1 * 512]);
        gl_lds16(gK0 + t0 * 4096 + 4096, &Kt[1][c0 * 512]);
        gl_lds16(gK1 + t0 * 4096 + 4096, &Kt[1][c1 * 512]);
        gl_lds16(gV0 + t0 * 64 + 64, &Vt[1][c0 * 512]);
        gl_lds16(gV1 + t0 * 64 + 64, &Vt[1][c1 * 512]);
        __syncthreads();

#pragma unroll
        for (int u = 0; u < 2; ++u) {
            // S^T = K * Q^T: C[m=key nf*16+quad*4+r][n=q=l16]  (QSCALE in Q)
            f32x4 st[4];
#pragma unroll
            for (int nf = 0; nf < 4; ++nf) {
                const bf16x8 kb0 = *(const bf16x8*)&Kt[u][nf * 1024 + koff0];
                const bf16x8 kb1 = *(const bf16x8*)&Kt[u][nf * 1024 + koff1];
                f32x4 z = {0.f, 0.f, 0.f, 0.f};
                z = MFMA16(kb0, qa[0], z);
                z = MFMA16(kb1, qa[1], z);
                st[nf] = z;
            }

            // exp in registers via compiler-visible single-instr intrinsic
            float e[16];
#pragma unroll
            for (int nf = 0; nf < 4; ++nf)
#pragma unroll
                for (int r = 0; r < 4; ++r) e[nf * 4 + r] = exp2_fast(st[nf][r]);
            bf16x8 pa[2];
            uint4 u0, u1;
            u0.x = pk_bf16(e[0], e[1]);   u0.y = pk_bf16(e[2], e[3]);
            u0.z = pk_bf16(e[4], e[5]);   u0.w = pk_bf16(e[6], e[7]);
            u1.x = pk_bf16(e[8], e[9]);   u1.y = pk_bf16(e[10], e[11]);
            u1.z = pk_bf16(e[12], e[13]); u1.w = pk_bf16(e[14], e[15]);
            __builtin_memcpy(&pa[0], &u0, 16);
            __builtin_memcpy(&pa[1], &u1, 16);
            // denominator: D[m][q] = sum_k P^T[k][q] (same bf16 P as numerator)
            lacc = MFMA16(ones, pa[0], lacc);
            lacc = MFMA16(ones, pa[1], lacc);

            // O^T += V^T * P^T: A = Vt[d][key'-sw], B = pa (registers)
#pragma unroll
            for (int df = 0; df < 4; ++df) {
                const bf16x8 vb0 = *(const bf16x8*)&Vt[u][df * 1024 + koff0];
                const bf16x8 vb1 = *(const bf16x8*)&Vt[u][df * 1024 + koff1];
                o[df] = MFMA16(vb0, pa[0], o[df]);
                o[df] = MFMA16(vb1, pa[1], o[df]);
            }
        }
        __syncthreads();
    }

    // epilogue: lacc already holds the full row sum for q-col l16
    const int b = bh >> 4, h = bh & 15;
    const float inv = 1.0f / lacc[0];
    const int token = b * 2048 + qrow + l16;
#pragma unroll
    for (int df = 0; df < 4; ++df) {
        uint2 pk;
        pk.x = pk_bf16(o[df][0] * inv, o[df][1] * inv);
        pk.y = pk_bf16(o[df][2] * inv, o[df][3] * inv);
        *(uint2*)(ssa + (size_t)token * 1024 + h * 64 + df * 16 + quad * 4) = pk;
    }
}

// ---------- launch ----------
extern "C" void kernel_launch(void* const* d_in, const int* in_sizes, int n_in,
                              void* d_out, int out_size, void* d_ws, size_t ws_size,
                              hipStream_t stream) {
    const float* ZT = (const float*)d_in[0];  // (2,2048,1024)
    const float* W = (const float*)d_in[1];   // (1024,1024)
    float* out = (float*)d_out;               // 2 x 4194304 fp32
    char* ws = (char*)d_ws;

    unsigned short* wbf   = (unsigned short*)(ws);                       // 2 MB
    unsigned short* wtbf  = (unsigned short*)(ws + 2u * 1024 * 1024);    // 2 MB
    unsigned short* ztu   = (unsigned short*)(ws + 4u * 1024 * 1024);    // 8 MB (b,h,n,dh_perm)
    unsigned short* ztut  = (unsigned short*)(ws + 12u * 1024 * 1024);   // 8 MB (b,h,dh,n_perm32)
    unsigned short* scr20 = (unsigned short*)(ws + 20u * 1024 * 1024);   // 8 MB: ztbf, then ssabf

    // W (straight + transpose) and ZT fp32->bf16, one launch
    cvt_k<<<2304, 256, 0, stream>>>(W, ZT, wbf, wtbf, scr20);
    // ZTU = ZT @ W^T (bf16 A via gl_lds16, double-buffered)
    gemm_bt_k<0><<<512, 256, 0, stream>>>((const __hip_bfloat16*)scr20,
                                          (const __hip_bfloat16*)wbf, ztu, ztut,
                                          nullptr, nullptr);
    // flash attention (pair-unrolled tiles + Q-prescale + intrinsic exp2)
    attn_k<<<1024, 256, 0, stream>>>(ztu, ztut, scr20);
    // mssa = ssa @ W, duplicated output (coalesced float4 epilogue)
    gemm_bt_k<1><<<512, 256, 0, stream>>>((const __hip_bfloat16*)scr20,
                                          (const __hip_bfloat16*)wtbf, nullptr, nullptr,
                                          out, out + 4194304);
}

// Round 15
// 143.604 us; speedup vs baseline: 1.1346x; 1.0234x over previous
//
#include <hip/hip_runtime.h>
#include <hip/hip_bf16.h>
#include <stdint.h>

// ---------- types ----------
typedef __attribute__((ext_vector_type(8))) short bf16x8;   // 8 bf16 in 4 VGPRs
typedef __attribute__((ext_vector_type(4))) float f32x4;

#define MFMA16(a, b, c) __builtin_amdgcn_mfma_f32_16x16x32_bf16(a, b, c, 0, 0, 0)

// async global->LDS, 16 bytes per lane; LDS dest = wave-uniform base + lane*16
typedef const __attribute__((address_space(1))) unsigned int* as1_u32p;
typedef __attribute__((address_space(3))) unsigned int* as3_u32p;
__device__ __forceinline__ void gl_lds16(const void* g, void* l) {
    __builtin_amdgcn_global_load_lds((as1_u32p)g, (as3_u32p)l, 16, 0, 0);
}

__device__ __forceinline__ unsigned short f2bs(float f) {
    __hip_bfloat16 h = __float2bfloat16(f);   // RNE
    unsigned short s;
    __builtin_memcpy(&s, &h, 2);
    return s;
}

// packed RNE f32x2 -> bf16x2 (v_cvt_pk_bf16_f32 on gfx950)
__device__ __forceinline__ unsigned int pk_bf16(float a, float b) {
    float2 f; f.x = a; f.y = b;
    __hip_bfloat162 h = __float22bfloat162_rn(f);
    unsigned int u;
    __builtin_memcpy(&u, &h, 4);
    return u;
}

// exp2 via the LLVM intrinsic: exactly one v_exp_f32, AND compiler-visible —
// the MFMA-write -> VALU-read hazard recognizer schedules it correctly.
// HISTORY: inline-asm v_exp_f32 reading an MFMA accumulator directly corrupted
// data (r1/r6 — INLINEASM is invisible to the hazard recognizer). r13 proved
// prescale + compiler-visible exp correct; r14 proved the intrinsic fast.
__device__ __forceinline__ float exp2_fast(float x) {
    return __builtin_amdgcn_exp2f(x);
}

// combined softmax scale: DH^-0.5 * log2(e); folded into the Q fragments in attn
#define QSCALE 0.18033688f

// ---------- fused convert: W fp32 -> bf16 (straight + transpose), ZT fp32 -> bf16 ----------
// blocks [0,256): W 64x64 tiles (LDS transpose for wtbf); blocks [256,2304): ZT stream-convert.
__global__ __launch_bounds__(256) void cvt_k(const float* __restrict__ w,
                                             const float* __restrict__ zt,
                                             unsigned short* __restrict__ wbf,
                                             unsigned short* __restrict__ wtbf,
                                             unsigned short* __restrict__ ztbf) {
    __shared__ __attribute__((aligned(16))) unsigned short T[64 * 72];  // 9 KB
    const int tid = threadIdx.x;
    if (blockIdx.x >= 256) {
        const int i = ((int)blockIdx.x - 256) * 2048 + tid * 8;
        const float4 v0 = *(const float4*)(zt + i);
        const float4 v1 = *(const float4*)(zt + i + 4);
        uint4 wv;
        wv.x = pk_bf16(v0.x, v0.y);
        wv.y = pk_bf16(v0.z, v0.w);
        wv.z = pk_bf16(v1.x, v1.y);
        wv.w = pk_bf16(v1.z, v1.w);
        *(uint4*)(ztbf + i) = wv;
        return;
    }
    const int b2 = blockIdx.x;               // 256 tiles: 16x16 of 64x64
    const int e0 = (b2 >> 4) * 64, d0 = (b2 & 15) * 64;
    const int el = tid >> 2;                 // 0..63
    const int dl = (tid & 3) * 16;           // 0,16,32,48
    const float* src = w + (size_t)(e0 + el) * 1024 + d0 + dl;
    unsigned short myv[16];
#pragma unroll
    for (int q = 0; q < 4; ++q) {
        const float4 v = *(const float4*)(src + q * 4);
        myv[q * 4 + 0] = f2bs(v.x);
        myv[q * 4 + 1] = f2bs(v.y);
        myv[q * 4 + 2] = f2bs(v.z);
        myv[q * 4 + 3] = f2bs(v.w);
    }
    // wbf straight (two 16B stores)
    *(bf16x8*)(wbf + (size_t)(e0 + el) * 1024 + d0 + dl) = *(const bf16x8*)&myv[0];
    *(bf16x8*)(wbf + (size_t)(e0 + el) * 1024 + d0 + dl + 8) = *(const bf16x8*)&myv[8];
    // LDS transpose: T[d_local][e_local] (natural)
#pragma unroll
    for (int q = 0; q < 16; ++q) T[(dl + q) * 72 + el] = myv[q];
    __syncthreads();
    // coalesced wtbf stores: row d, 64 e contiguous
#pragma unroll
    for (int p = 0; p < 2; ++p) {
        const int idx = p * 256 + tid;
        const int dd = idx >> 3, c = (idx & 7) * 8;
        const bf16x8 v = *(const bf16x8*)&T[dd * 72 + c];
        *(bf16x8*)(wtbf + (size_t)(d0 + dd) * 1024 + e0 + c) = v;
    }
}

// ---------- GEMM: C[M,N] = A[M,K] * B[N,K]^T, tile 64x128, BK=64, 4 waves ----------
// Double-buffered (48 KB LDS): stage kt+1 while computing kt; one barrier per K-step.
// LDS tiles stored as [row][64] with XOR chunk swizzle -> conflict-free ds_read_b128.
// EPI 0: C -> ztu bf16 + ztut via LDS transpose (token perm in 32-grps for attn).
// EPI 1: C -> out0, out1 fp32 via fp32 LDS transpose, float4 coalesced.
template <int EPI>
__global__ __launch_bounds__(256, 2) void gemm_bt_k(
    const __hip_bfloat16* __restrict__ Abf, const __hip_bfloat16* __restrict__ B,
    unsigned short* __restrict__ ztu, unsigned short* __restrict__ ztut,
    float* __restrict__ out0, float* __restrict__ out1) {
    __shared__ __attribute__((aligned(16))) unsigned short smem[24576];  // 48 KB: 2 x (A 8KB + B 16KB)
    unsigned short* Tb = smem;          // EPI-0 epilogue reuse: [128][72] = 18 KB

    const int p = blockIdx.x;
    const int bm = (p & 7) * 8 + ((p >> 3) & 7);   // same-bm blocks share an XCD
    const int bn = p >> 6;
    const int tid = threadIdx.x;
    const int wave = tid >> 6, lane = tid & 63;
    const int wm = wave >> 1, wn = wave & 1;   // wave tile: 32 rows x 64 cols
    const int quad = lane >> 4, l16 = lane & 15;

    f32x4 acc[2][4] = {};

    // staging: 8-row 512-short chunks, lane covers (lrow, swizzled col group)
    const int lrow = lane >> 3;
    const int sw = (lane & 7) ^ lrow;
    const __hip_bfloat16* Ag0 = Abf + (size_t)(bm * 64 + (2 * wave) * 8 + lrow) * 1024 + sw * 8;
    const __hip_bfloat16* Ag1 = Ag0 + 8 * 1024;
    const __hip_bfloat16* Bg0 = B + (size_t)(bn * 128 + (4 * wave) * 8 + lrow) * 1024 + sw * 8;
    const __hip_bfloat16* Bg1 = Bg0 + 8 * 1024;
    const __hip_bfloat16* Bg2 = Bg0 + 16 * 1024;
    const __hip_bfloat16* Bg3 = Bg0 + 24 * 1024;

    auto stage = [&](int ko, unsigned short* sb) {
        gl_lds16(Ag0 + ko, sb + (2 * wave) * 512);
        gl_lds16(Ag1 + ko, sb + (2 * wave + 1) * 512);
        gl_lds16(Bg0 + ko, sb + 4096 + (4 * wave) * 512);
        gl_lds16(Bg1 + ko, sb + 4096 + (4 * wave + 1) * 512);
        gl_lds16(Bg2 + ko, sb + 4096 + (4 * wave + 2) * 512);
        gl_lds16(Bg3 + ko, sb + 4096 + (4 * wave + 3) * 512);
    };

    // swizzled read offsets: chunk (h*4+quad)^(l16&7); ^4 on chunk == ^32 on elems
    const int ch0 = (quad ^ (l16 & 7)) * 8;
    const int ch1 = ch0 ^ 32;
    const int raA = (wm * 32 + l16) * 64;
    const int raB = (wn * 64 + l16) * 64;

    stage(0, smem);
    __syncthreads();

    for (int kt = 0; kt < 16; ++kt) {
        unsigned short* const sb = smem + (kt & 1) * 12288;
        if (kt < 15) stage((kt + 1) << 6, smem + (((kt & 1) ^ 1) * 12288));
        bf16x8 af[2][2], bfr[2][4];
#pragma unroll
        for (int i = 0; i < 2; ++i) {
            af[0][i] = *(const bf16x8*)&sb[raA + i * 1024 + ch0];
            af[1][i] = *(const bf16x8*)&sb[raA + i * 1024 + ch1];
        }
#pragma unroll
        for (int j = 0; j < 4; ++j) {
            bfr[0][j] = *(const bf16x8*)&sb[4096 + raB + j * 1024 + ch0];
            bfr[1][j] = *(const bf16x8*)&sb[4096 + raB + j * 1024 + ch1];
        }
#pragma unroll
        for (int h = 0; h < 2; ++h)
#pragma unroll
            for (int i = 0; i < 2; ++i)
#pragma unroll
                for (int j = 0; j < 4; ++j) acc[i][j] = MFMA16(af[h][i], bfr[h][j], acc[i][j]);
        __syncthreads();
    }

    if (EPI == 0) {
        const int h = bn * 2 + wn;           // e = bn*128 + wn*64 + j*16+l16 -> j-independent
        const int bb = bm >> 5;              // batch
        const int nb = (bm & 31) * 64;       // token base within batch
        const size_t hb = (size_t)(bb * 16 + h) * 131072;
#pragma unroll
        for (int i = 0; i < 2; ++i) {
#pragma unroll
            for (int r = 0; r < 4; ++r) {
                const int n = nb + wm * 32 + i * 16 + quad * 4 + r;
                uint2 pk;
                pk.x = pk_bf16(acc[i][0][r], acc[i][1][r]);
                pk.y = pk_bf16(acc[i][2][r], acc[i][3][r]);
                // ztu: dh stored-permuted (4*l16 + j) -> one packed b64 store
                *(uint2*)(ztu + hb + n * 64 + l16 * 4) = pk;
                // Tb[e_local][np_local]: key perm within 32-groups for S^T trick:
                // n_local = wm*32 + i*16 + quad*4 + r -> np = wm*32 + quad*8 + i*4 + r
                const int npl = wm * 32 + quad * 8 + i * 4 + r;
                Tb[(wn * 64 + 0 + l16) * 72 + npl] = (unsigned short)(pk.x & 0xffff);
                Tb[(wn * 64 + 16 + l16) * 72 + npl] = (unsigned short)(pk.x >> 16);
                Tb[(wn * 64 + 32 + l16) * 72 + npl] = (unsigned short)(pk.y & 0xffff);
                Tb[(wn * 64 + 48 + l16) * 72 + npl] = (unsigned short)(pk.y >> 16);
            }
        }
        __syncthreads();
        // ztut: coalesced b128 stores, rows = natural dh, cols = permuted tokens
#pragma unroll
        for (int ee = 0; ee < 4; ++ee) {
            const int e_local = wave * 32 + ee * 8 + (lane >> 3);
            const int nc = (lane & 7) * 8;
            const bf16x8 v = *(const bf16x8*)&Tb[e_local * 72 + nc];
            const int hh = bn * 2 + (e_local >> 6);
            const int dh = e_local & 63;
            *(bf16x8*)(ztut + (size_t)(bb * 16 + hh) * 131072 + dh * 2048 + nb + nc) = v;
        }
    } else {
        // coalesced fp32 epilogue: LDS transpose [64][132] fp32, then 512B-contiguous
        // float4 stores.
        float* Tf = (float*)smem;
        // K-loop's final __syncthreads() already fenced all LDS reads.
#pragma unroll
        for (int i = 0; i < 2; ++i)
#pragma unroll
            for (int r = 0; r < 4; ++r) {
                const int ml = wm * 32 + i * 16 + quad * 4 + r;
#pragma unroll
                for (int j = 0; j < 4; ++j)
                    Tf[ml * 132 + wn * 64 + j * 16 + l16] = acc[i][j][r];
            }
        __syncthreads();
#pragma unroll
        for (int q = 0; q < 8; ++q) {
            const int idx = q * 256 + tid;        // 0..2047
            const int row = idx >> 5;             // 0..63
            const int c4 = (idx & 31) * 4;        // 0..124
            const float4 v = *(const float4*)&Tf[row * 132 + c4];
            const size_t off = (size_t)(bm * 64 + row) * 1024 + bn * 128 + c4;
            *(float4*)(out0 + off) = v;
            *(float4*)(out1 + off) = v;
        }
    }
}

// ---------- flash attention, transposed (register-P) structure ----------
// LDS-REDUNDANCY FIX: r14's counters imply ~81% of attn wall is ds_read_b128
// port time (2.1M reads: all 4 waves of a block read IDENTICAL K/V fragments,
// each wave carrying only 16 q-rows). New geometry = r2's proven 32-q-rows/wave
// g-loop (HALF the LDS reads per FLOP, 1.05M total) combined with every
// since-proven fix for r2's stall problem: pair-unrolled tiles (r11, halves
// barriers), ones-MFMA denominator (r4), Q-prescale + intrinsic exp2 (r13/r14).
// Grid 512 = 32 bh x 16 q-tiles of 128 rows; 2 blocks/CU, 32 KB LDS.
__global__ __launch_bounds__(256, 2) void attn_k(const unsigned short* __restrict__ ztu,
                                                 const unsigned short* __restrict__ ztut,
                                                 unsigned short* __restrict__ ssa) {
    __shared__ __attribute__((aligned(16))) unsigned short Kt[2][4096];   // [key][d-sw]
    __shared__ __attribute__((aligned(16))) unsigned short Vt[2][4096];   // [d][key'-sw]
    const int p = blockIdx.x;
    const int ii = p >> 3;                    // 0..63
    const int bh = (p & 7) * 4 + (ii >> 4);   // 32 bh, XCD-swizzled
    const int qt = ii & 15;                   // 16 q-tiles of 128 rows
    const int tid = threadIdx.x, wave = tid >> 6, lane = tid & 63;
    const int quad = lane >> 4, l16 = lane & 15;
    const unsigned short* base = ztu + (size_t)bh * 131072;
    const unsigned short* baseT = ztut + (size_t)bh * 131072;

    // Q fragments (B-operand): 2 row-groups x 2 k-chunks (32 q-rows/wave),
    // QSCALE folded in once (r13-verified; safe with compiler-visible exp)
    const int qb = qt * 128 + wave * 32;
    bf16x8 qa[2][2];
#pragma unroll
    for (int g = 0; g < 2; ++g) {
        qa[g][0] = *(const bf16x8*)(base + (qb + g * 16 + l16) * 64 + quad * 8);
        qa[g][1] = *(const bf16x8*)(base + (qb + g * 16 + l16) * 64 + 32 + quad * 8);
#pragma unroll
        for (int w = 0; w < 2; ++w) {
            bf16x8 v = qa[g][w], r;
#pragma unroll
            for (int z = 0; z < 8; z += 2) {
                const float f0 = __uint_as_float(((unsigned)(unsigned short)v[z]) << 16) * QSCALE;
                const float f1 = __uint_as_float(((unsigned)(unsigned short)v[z + 1]) << 16) * QSCALE;
                const unsigned u = pk_bf16(f0, f1);
                r[z] = (short)(u & 0xffff);
                r[z + 1] = (short)(u >> 16);
            }
            qa[g][w] = r;
        }
    }

    f32x4 o[2][4] = {};
    f32x4 lacc[2] = {};   // softmax denominators via ones-MFMA (all rows = col sum)
    bf16x8 ones;
#pragma unroll
    for (int z = 0; z < 8; ++z) ones[z] = (short)0x3f80;   // bf16 1.0

    // staging: tile = 8 chunks of 1KB; wave w stages chunks {2w,2w+1} of K and V.
    // chunk c covers rows c*8+(lane>>3); swizzled source group = (lane&7)^(lane>>3)
    const int c0 = wave * 2, c1 = c0 + 1;
    const int lrow = lane >> 3;
    const int sw = (lane & 7) ^ lrow;
    const unsigned short* gK0 = base + (c0 * 8 + lrow) * 64 + sw * 8;
    const unsigned short* gK1 = base + (c1 * 8 + lrow) * 64 + sw * 8;
    const unsigned short* gV0 = baseT + (size_t)(c0 * 8 + lrow) * 2048 + sw * 8;
    const unsigned short* gV1 = baseT + (size_t)(c1 * 8 + lrow) * 2048 + sw * 8;

    // swizzled read offsets (elements)
    const int swq = (quad ^ (l16 & 7));
    const int koff0 = l16 * 64 + swq * 8;          // + {nf,df}*1024 per row-group
    const int koff1 = l16 * 64 + (swq ^ 4) * 8;

    for (int tp = 0; tp < 16; ++tp) {
        const int t0 = tp * 2;                     // tiles t0 and t0+1 this pass
        gl_lds16(gK0 + t0 * 4096, &Kt[0][c0 * 512]);
        gl_lds16(gK1 + t0 * 4096, &Kt[0][c1 * 512]);
        gl_lds16(gV0 + t0 * 64, &Vt[0][c0 * 512]);
        gl_lds16(gV1 + t0 * 64, &Vt[0][c1 * 512]);
        gl_lds16(gK0 + t0 * 4096 + 4096, &Kt[1][c0 * 512]);
        gl_lds16(gK1 + t0 * 4096 + 4096, &Kt[1][c1 * 512]);
        gl_lds16(gV0 + t0 * 64 + 64, &Vt[1][c0 * 512]);
        gl_lds16(gV1 + t0 * 64 + 64, &Vt[1][c1 * 512]);
        __syncthreads();

#pragma unroll
        for (int u = 0; u < 2; ++u) {
            // S^T = K * Q^T: C[m=key nf*16+quad*4+r][n=q=l16], per g  (QSCALE in Q)
            f32x4 st[2][4];
#pragma unroll
            for (int nf = 0; nf < 4; ++nf) {
                const bf16x8 kb0 = *(const bf16x8*)&Kt[u][nf * 1024 + koff0];
                const bf16x8 kb1 = *(const bf16x8*)&Kt[u][nf * 1024 + koff1];
#pragma unroll
                for (int g = 0; g < 2; ++g) {
                    f32x4 z = {0.f, 0.f, 0.f, 0.f};
                    z = MFMA16(kb0, qa[g][0], z);
                    z = MFMA16(kb1, qa[g][1], z);
                    st[g][nf] = z;
                }
            }

            // exp in registers via compiler-visible single-instr intrinsic;
            // pack P^T B-fragments: key' = quad*8 + mb*4 + r
            bf16x8 pa[2][2];
#pragma unroll
            for (int g = 0; g < 2; ++g) {
                float e[16];
#pragma unroll
                for (int nf = 0; nf < 4; ++nf)
#pragma unroll
                    for (int r = 0; r < 4; ++r) e[nf * 4 + r] = exp2_fast(st[g][nf][r]);
                uint4 u0, u1;
                u0.x = pk_bf16(e[0], e[1]);   u0.y = pk_bf16(e[2], e[3]);
                u0.z = pk_bf16(e[4], e[5]);   u0.w = pk_bf16(e[6], e[7]);
                u1.x = pk_bf16(e[8], e[9]);   u1.y = pk_bf16(e[10], e[11]);
                u1.z = pk_bf16(e[12], e[13]); u1.w = pk_bf16(e[14], e[15]);
                __builtin_memcpy(&pa[g][0], &u0, 16);
                __builtin_memcpy(&pa[g][1], &u1, 16);
                // denominator: D[m][q] = sum_k P^T[k][q] (same bf16 P as numerator)
                lacc[g] = MFMA16(ones, pa[g][0], lacc[g]);
                lacc[g] = MFMA16(ones, pa[g][1], lacc[g]);
            }

            // O^T += V^T * P^T: A = Vt[d][key'-sw], B = pa (registers)
#pragma unroll
            for (int df = 0; df < 4; ++df) {
                const bf16x8 vb0 = *(const bf16x8*)&Vt[u][df * 1024 + koff0];
                const bf16x8 vb1 = *(const bf16x8*)&Vt[u][df * 1024 + koff1];
#pragma unroll
                for (int g = 0; g < 2; ++g) {
                    o[g][df] = MFMA16(vb0, pa[g][0], o[g][df]);
                    o[g][df] = MFMA16(vb1, pa[g][1], o[g][df]);
                }
            }
        }
        __syncthreads();
    }

    // epilogue: lacc[g] already holds the full row sum for q-col l16
    const int b = bh >> 4, h = bh & 15;
#pragma unroll
    for (int g = 0; g < 2; ++g) {
        const float inv = 1.0f / lacc[g][0];
        const int token = b * 2048 + qb + g * 16 + l16;
#pragma unroll
        for (int df = 0; df < 4; ++df) {
            uint2 pk;
            pk.x = pk_bf16(o[g][df][0] * inv, o[g][df][1] * inv);
            pk.y = pk_bf16(o[g][df][2] * inv, o[g][df][3] * inv);
            *(uint2*)(ssa + (size_t)token * 1024 + h * 64 + df * 16 + quad * 4) = pk;
        }
    }
}

// ---------- launch ----------
extern "C" void kernel_launch(void* const* d_in, const int* in_sizes, int n_in,
                              void* d_out, int out_size, void* d_ws, size_t ws_size,
                              hipStream_t stream) {
    const float* ZT = (const float*)d_in[0];  // (2,2048,1024)
    const float* W = (const float*)d_in[1];   // (1024,1024)
    float* out = (float*)d_out;               // 2 x 4194304 fp32
    char* ws = (char*)d_ws;

    unsigned short* wbf   = (unsigned short*)(ws);                       // 2 MB
    unsigned short* wtbf  = (unsigned short*)(ws + 2u * 1024 * 1024);    // 2 MB
    unsigned short* ztu   = (unsigned short*)(ws + 4u * 1024 * 1024);    // 8 MB (b,h,n,dh_perm)
    unsigned short* ztut  = (unsigned short*)(ws + 12u * 1024 * 1024);   // 8 MB (b,h,dh,n_perm32)
    unsigned short* scr20 = (unsigned short*)(ws + 20u * 1024 * 1024);   // 8 MB: ztbf, then ssabf

    // W (straight + transpose) and ZT fp32->bf16, one launch
    cvt_k<<<2304, 256, 0, stream>>>(W, ZT, wbf, wtbf, scr20);
    // ZTU = ZT @ W^T (bf16 A via gl_lds16, double-buffered)
    gemm_bt_k<0><<<512, 256, 0, stream>>>((const __hip_bfloat16*)scr20,
                                          (const __hip_bfloat16*)wbf, ztu, ztut,
                                          nullptr, nullptr);
    // flash attention (32q/wave g-loop + pair-unroll + prescale + intrinsic exp2)
    attn_k<<<512, 256, 0, stream>>>(ztu, ztut, scr20);
    // mssa = ssa @ W, duplicated output (coalesced float4 epilogue)
    gemm_bt_k<1><<<512, 256, 0, stream>>>((const __hip_bfloat16*)scr20,
                                          (const __hip_bfloat16*)wtbf, nullptr, nullptr,
                                          out, out + 4194304);
}